// Round 1
// baseline (5187.580 us; speedup 1.0000x reference)
//
#include <hip/hip_runtime.h>
#include <math.h>

#define NT 256

// ---------------- prep kernels: transpose weights into workspace ----------------
// WcatT[196][640]: col c<196 -> W1[c][f], c<392 -> W2[c-196][f], c<588 -> W3[c-392][f], else 0
__global__ void k_prep_cat(const float* __restrict__ W1, const float* __restrict__ b1,
                           const float* __restrict__ W2, const float* __restrict__ b2,
                           const float* __restrict__ W3, const float* __restrict__ b3,
                           float* __restrict__ WcatT, float* __restrict__ bcat) {
  int idx = blockIdx.x * NT + threadIdx.x;
  if (idx < 196 * 640) {
    int f = idx / 640, c = idx - f * 640;
    float v = 0.f;
    if (c < 196)      v = W1[c * 196 + f];
    else if (c < 392) v = W2[(c - 196) * 196 + f];
    else if (c < 588) v = W3[(c - 392) * 196 + f];
    WcatT[idx] = v;
  }
  if (idx < 640) {
    float v = 0.f;
    if (idx < 196)      v = b1[idx];
    else if (idx < 392) v = b2[idx - 196];
    else if (idx < 588) v = b3[idx - 392];
    bcat[idx] = v;
  }
}

// WdT[784][896] = Wd[c][f] transposed, zero-padded cols 784..895
__global__ void k_prep_dec(const float* __restrict__ Wd, float* __restrict__ WdT) {
  int idx = blockIdx.x * NT + threadIdx.x;
  if (idx >= 784 * 896) return;
  int f = idx / 896, c = idx - f * 896;
  WdT[idx] = (c < 784) ? Wd[c * 784 + f] : 0.f;
}

// ---------------- fused capsule net ----------------
// 8 elems per workgroup; h lives in LDS across all 8 iterations + decoder.
__global__ __launch_bounds__(NT, 2)
void k_capsnet(const float* __restrict__ x,
               const float* __restrict__ WcatT, const float* __restrict__ bcat,
               const float* __restrict__ Wd1T, const float* __restrict__ bd1,
               const float* __restrict__ Wd2T, const float* __restrict__ bd2,
               const float* __restrict__ Wo,  const float* __restrict__ bo,
               float* __restrict__ out) {
  __shared__ __align__(16) float v_s[8 * 784];        // h / v tile, [elem][t*196+f]
  __shared__ __align__(16) float qk_s[2 * 8 * 784];   // q then k; reused as d1 in decoder
  __shared__ float sc_s[128];                          // scores/probs, logits

  const int tid = threadIdx.x;
  const int b0  = blockIdx.x * 8;

  for (int j = tid; j < 8 * 784; j += NT) v_s[j] = x[b0 * 784 + j];
  __syncthreads();

  const int ct = tid & 63;      // 64 col-threads (one wave = one row-group)
  const int rg = tid >> 6;      // 4 row-groups, 8 rows (= 2 elems x 4 t) each
  const int vbase = rg * 1568;  // rg*2 elems * 784 floats

  for (int it = 0; it < 8; ++it) {
    // ---- GEMM: [32 rows=(elem,t)] x [640 cols=(q|k|u|pad)] over K=196 ----
    float acc[8][10];
    #pragma unroll
    for (int i = 0; i < 10; ++i) {
      float bb = bcat[ct + 64 * i];
      #pragma unroll
      for (int rr = 0; rr < 8; ++rr) acc[rr][i] = bb;
    }
    for (int fl = 0; fl < 196; fl += 4) {
      float4 a4[8];
      #pragma unroll
      for (int rr = 0; rr < 8; ++rr)
        a4[rr] = *reinterpret_cast<const float4*>(&v_s[vbase + rr * 196 + fl]);
      #pragma unroll
      for (int sub = 0; sub < 4; ++sub) {
        float w[10];
        #pragma unroll
        for (int i = 0; i < 10; ++i) w[i] = WcatT[(fl + sub) * 640 + ct + 64 * i];
        #pragma unroll
        for (int rr = 0; rr < 8; ++rr) {
          float av = (sub == 0) ? a4[rr].x : (sub == 1) ? a4[rr].y : (sub == 2) ? a4[rr].z : a4[rr].w;
          #pragma unroll
          for (int i = 0; i < 10; ++i) acc[rr][i] = fmaf(av, w[i], acc[rr][i]);
        }
      }
    }
    // ---- scatter q,k to LDS (u stays in registers) ----
    #pragma unroll
    for (int rr = 0; rr < 8; ++rr) {
      #pragma unroll
      for (int i = 0; i < 10; ++i) {
        int c = ct + 64 * i;
        if (c < 196)      qk_s[vbase + rr * 196 + c] = acc[rr][i];
        else if (c < 392) qk_s[6272 + vbase + rr * 196 + (c - 196)] = acc[rr][i];
      }
    }
    __syncthreads();
    // ---- scores[elem][t][s] = q[t] . k[s]  (128 dots of length 196) ----
    if (tid < 128) {
      int qoff = (tid >> 2) * 196;                                   // (elem*4+t)*196
      int koff = 6272 + (((tid >> 4) << 2) + (tid & 3)) * 196;       // (elem*4+s)*196
      float s = 0.f;
      for (int fl = 0; fl < 196; fl += 4) {
        float4 qa = *reinterpret_cast<const float4*>(&qk_s[qoff + fl]);
        float4 kb = *reinterpret_cast<const float4*>(&qk_s[koff + fl]);
        s += qa.x * kb.x + qa.y * kb.y + qa.z * kb.z + qa.w * kb.w;
      }
      sc_s[tid] = s;
    }
    __syncthreads();
    // ---- softmax over s (4-wide), in place ----
    if (tid < 32) {
      int base = tid * 4;
      float s0 = sc_s[base + 0], s1 = sc_s[base + 1], s2 = sc_s[base + 2], s3 = sc_s[base + 3];
      float m = fmaxf(fmaxf(s0, s1), fmaxf(s2, s3));
      float e0 = __expf(s0 - m), e1 = __expf(s1 - m), e2 = __expf(s2 - m), e3 = __expf(s3 - m);
      float inv = 1.f / (e0 + e1 + e2 + e3);
      sc_s[base + 0] = e0 * inv; sc_s[base + 1] = e1 * inv;
      sc_s[base + 2] = e2 * inv; sc_s[base + 3] = e3 * inv;
    }
    __syncthreads();
    // ---- PV: h[elem][t][f] = sum_s p[t][s] * u[s][f], u from registers ----
    #pragma unroll
    for (int i = 0; i < 10; ++i) {
      int c = ct + 64 * i;
      if (c >= 392 && c < 588) {
        int f = c - 392;
        #pragma unroll
        for (int el = 0; el < 2; ++el) {
          int elem = rg * 2 + el;
          float u0 = acc[el * 4 + 0][i], u1 = acc[el * 4 + 1][i];
          float u2 = acc[el * 4 + 2][i], u3 = acc[el * 4 + 3][i];
          #pragma unroll
          for (int tt = 0; tt < 4; ++tt) {
            const float* p = &sc_s[(elem * 4 + tt) * 4];
            v_s[(elem * 4 + tt) * 196 + f] =
                fmaf(p[0], u0, fmaf(p[1], u1, fmaf(p[2], u2, p[3] * u3)));
          }
        }
      }
    }
    __syncthreads();
  }

  // ---------------- decoder (fused): relu(h Wd1^T + b) Wd2^T + b -> Wo^T -> softmax ----------------
  const int ct2 = tid & 127;
  const int rg2 = tid >> 7;   // 2 row-groups of 4 elems
  {
    float acc[4][7];
    // ---- layer 1 ----
    #pragma unroll
    for (int i = 0; i < 7; ++i) {
      int c = ct2 + 128 * i;
      float bb = (c < 784) ? bd1[c] : 0.f;
      #pragma unroll
      for (int rr = 0; rr < 4; ++rr) acc[rr][i] = bb;
    }
    for (int fl = 0; fl < 784; fl += 4) {
      float4 a4[4];
      #pragma unroll
      for (int rr = 0; rr < 4; ++rr)
        a4[rr] = *reinterpret_cast<const float4*>(&v_s[(rg2 * 4 + rr) * 784 + fl]);
      #pragma unroll
      for (int sub = 0; sub < 4; ++sub) {
        float w[7];
        #pragma unroll
        for (int i = 0; i < 7; ++i) w[i] = Wd1T[(fl + sub) * 896 + ct2 + 128 * i];
        #pragma unroll
        for (int rr = 0; rr < 4; ++rr) {
          float av = (sub == 0) ? a4[rr].x : (sub == 1) ? a4[rr].y : (sub == 2) ? a4[rr].z : a4[rr].w;
          #pragma unroll
          for (int i = 0; i < 7; ++i) acc[rr][i] = fmaf(av, w[i], acc[rr][i]);
        }
      }
    }
    __syncthreads();
    #pragma unroll
    for (int rr = 0; rr < 4; ++rr) {
      #pragma unroll
      for (int i = 0; i < 7; ++i) {
        int c = ct2 + 128 * i;
        if (c < 784) qk_s[(rg2 * 4 + rr) * 784 + c] = fmaxf(acc[rr][i], 0.f);
      }
    }
    __syncthreads();
    // ---- layer 2 ----
    #pragma unroll
    for (int i = 0; i < 7; ++i) {
      int c = ct2 + 128 * i;
      float bb = (c < 784) ? bd2[c] : 0.f;
      #pragma unroll
      for (int rr = 0; rr < 4; ++rr) acc[rr][i] = bb;
    }
    for (int fl = 0; fl < 784; fl += 4) {
      float4 a4[4];
      #pragma unroll
      for (int rr = 0; rr < 4; ++rr)
        a4[rr] = *reinterpret_cast<const float4*>(&qk_s[(rg2 * 4 + rr) * 784 + fl]);
      #pragma unroll
      for (int sub = 0; sub < 4; ++sub) {
        float w[7];
        #pragma unroll
        for (int i = 0; i < 7; ++i) w[i] = Wd2T[(fl + sub) * 896 + ct2 + 128 * i];
        #pragma unroll
        for (int rr = 0; rr < 4; ++rr) {
          float av = (sub == 0) ? a4[rr].x : (sub == 1) ? a4[rr].y : (sub == 2) ? a4[rr].z : a4[rr].w;
          #pragma unroll
          for (int i = 0; i < 7; ++i) acc[rr][i] = fmaf(av, w[i], acc[rr][i]);
        }
      }
    }
    #pragma unroll
    for (int rr = 0; rr < 4; ++rr) {
      #pragma unroll
      for (int i = 0; i < 7; ++i) {
        int c = ct2 + 128 * i;
        if (c < 784) v_s[(rg2 * 4 + rr) * 784 + c] = acc[rr][i];   // d2 into v_s
      }
    }
    __syncthreads();
  }
  // ---- logits + softmax ----
  if (tid < 80) {
    int elem = tid / 10, n = tid - elem * 10;
    const float* d2 = &v_s[elem * 784];
    const float* wo = &Wo[n * 784];
    float s = bo[n];
    for (int fl = 0; fl < 784; fl += 4) {
      float4 da = *reinterpret_cast<const float4*>(&d2[fl]);
      float4 wa = *reinterpret_cast<const float4*>(&wo[fl]);
      s += da.x * wa.x + da.y * wa.y + da.z * wa.z + da.w * wa.w;
    }
    sc_s[tid] = s;
  }
  __syncthreads();
  if (tid < 8) {
    float l[10], m = -1e30f;
    #pragma unroll
    for (int n = 0; n < 10; ++n) { l[n] = sc_s[tid * 10 + n]; m = fmaxf(m, l[n]); }
    float sum = 0.f;
    #pragma unroll
    for (int n = 0; n < 10; ++n) { l[n] = __expf(l[n] - m); sum += l[n]; }
    float inv = 1.f / sum;
    #pragma unroll
    for (int n = 0; n < 10; ++n) out[(b0 + tid) * 10 + n] = l[n] * inv;
  }
}

extern "C" void kernel_launch(void* const* d_in, const int* in_sizes, int n_in,
                              void* d_out, int out_size, void* d_ws, size_t ws_size,
                              hipStream_t stream) {
  const float* x   = (const float*)d_in[0];
  const float* W1  = (const float*)d_in[1];
  const float* b1  = (const float*)d_in[2];
  const float* W2  = (const float*)d_in[3];
  const float* b2  = (const float*)d_in[4];
  const float* W3  = (const float*)d_in[5];
  const float* b3  = (const float*)d_in[6];
  const float* Wd1 = (const float*)d_in[7];
  const float* bd1 = (const float*)d_in[8];
  const float* Wd2 = (const float*)d_in[9];
  const float* bd2 = (const float*)d_in[10];
  const float* Wo  = (const float*)d_in[11];
  const float* bo  = (const float*)d_in[12];
  float* out = (float*)d_out;

  float* ws    = (float*)d_ws;
  float* WcatT = ws;                      // 196*640
  float* bcat  = WcatT + 196 * 640;       // 640
  float* Wd1T  = bcat + 640;              // 784*896
  float* Wd2T  = Wd1T + 784 * 896;        // 784*896   total ~6.1 MB

  k_prep_cat<<<(196 * 640 + NT - 1) / NT, NT, 0, stream>>>(W1, b1, W2, b2, W3, b3, WcatT, bcat);
  k_prep_dec<<<(784 * 896 + NT - 1) / NT, NT, 0, stream>>>(Wd1, Wd1T);
  k_prep_dec<<<(784 * 896 + NT - 1) / NT, NT, 0, stream>>>(Wd2, Wd2T);
  k_capsnet<<<32768 / 8, NT, 0, stream>>>(x, WcatT, bcat, Wd1T, bd1, Wd2T, bd2, Wo, bo, out);
}

// Round 2
// 3328.864 us; speedup vs baseline: 1.5584x; 1.5584x over previous
//
#include <hip/hip_runtime.h>
#include <math.h>

#define NT 256
typedef _Float16 f16;
typedef _Float16 half8 __attribute__((ext_vector_type(8)));
typedef float floatx4 __attribute__((ext_vector_type(4)));

// ---------------- workspace layout (bytes) ----------------
// Wcap_hi : 448*224*2 = 200704   @ 0
// Wcap_lo : 200704               @ 200704
// bcap    : 448*4    = 1792      @ 401408
// Wd1h    : 832*800*2 = 1331200  @ 403200
// Wd2h    : 1331200              @ 1734400
// WoT     : 784*16*4 = 50176     @ 3065600
#define WCAP_LO_OFF 200704
#define BCAP_OFF    401408
#define WD1_OFF     403200
#define WD2_OFF     1734400
#define WOT_OFF     3065600

// Wcap[n][k] (n<196: G^T row = sum_f W1[f][k]*W2[f][n]; n==196: g[k]=sum_f b1[f]*W2[f][k];
//             224<=n<420: W3[n-224][k]; else 0), split into fp16 hi/lo.
__global__ void k_prep_wcap(const float* __restrict__ W1, const float* __restrict__ b1,
                            const float* __restrict__ W2,
                            const float* __restrict__ W3, const float* __restrict__ b3,
                            f16* __restrict__ Wch, f16* __restrict__ Wcl,
                            float* __restrict__ bcap) {
  int idx = blockIdx.x * NT + threadIdx.x;
  if (idx >= 448 * 224) return;
  int n = idx / 224, k = idx - n * 224;
  float v = 0.f;
  if (k < 196) {
    if (n < 196) {
      float s = 0.f;
      for (int f = 0; f < 196; ++f) s += W1[f * 196 + k] * W2[f * 196 + n];
      v = s;
    } else if (n == 196) {
      float s = 0.f;
      for (int f = 0; f < 196; ++f) s += b1[f] * W2[f * 196 + k];
      v = s;
    } else if (n >= 224 && n < 420) {
      v = W3[(n - 224) * 196 + k];
    }
  }
  f16 hi = (f16)v;
  Wch[idx] = hi;
  Wcl[idx] = (f16)(v - (float)hi);
  if (k == 0) bcap[n] = (n >= 224 && n < 420) ? b3[n - 224] : 0.f;
}

// Wd16[832][800] fp16, zero-padded
__global__ void k_prep_wd(const float* __restrict__ Wd, f16* __restrict__ W16) {
  int idx = blockIdx.x * NT + threadIdx.x;
  if (idx >= 832 * 800) return;
  int n = idx / 800, k = idx - n * 800;
  W16[idx] = (f16)((n < 784 && k < 784) ? Wd[n * 784 + k] : 0.f);
}

// WoT[784][16] fp32 (n<10 valid)
__global__ void k_prep_wo(const float* __restrict__ Wo, float* __restrict__ WoT) {
  int idx = blockIdx.x * NT + threadIdx.x;
  if (idx >= 784 * 16) return;
  int f = idx >> 4, n = idx & 15;
  WoT[idx] = (n < 10) ? Wo[n * 784 + f] : 0.f;
}

// ---------------- fused capsule net, split-fp16 MFMA ----------------
// 16 elems/wg (M=64 rows of (elem,t)); v as hi+lo fp16 in LDS (fp32-equivalent).
// Capsule GEMM: [64 x 448] = v * Wcap^T; cols 0..223 = Y(=vG, col196=Z=g.v), 224..419 = u.
__global__ __launch_bounds__(NT, 2)
void k_caps(const float* __restrict__ x,
            const f16* __restrict__ Wch, const f16* __restrict__ Wcl,
            const float* __restrict__ bcap,
            const f16* __restrict__ Wd1, const float* __restrict__ bd1,
            const f16* __restrict__ Wd2, const float* __restrict__ bd2,
            const float* __restrict__ WoT, const float* __restrict__ bo,
            float* __restrict__ out) {
  __shared__ __align__(16) char smem[64768];
  f16*   vAhi  = (f16*)smem;                 // [64][232] fp16 (pad cols 196..231 = 0)
  f16*   vAlo  = (f16*)(smem + 29696);       // [64][232]
  float* Spart = (float*)(smem + 59392);     // [4 waves][64 rows][4 s]
  float* Sful  = (float*)(smem + 63488);     // [64][4] scores -> probs
  float* Zl    = (float*)(smem + 64512);     // [64] Z_row = g . v_row

  const int tid  = threadIdx.x;
  const int w    = tid >> 6;
  const int lane = tid & 63;
  const int l15  = lane & 15;
  const int quad = lane >> 4;
  const int e0   = blockIdx.x * 16;

  // ---- load x -> vA hi/lo; zero pad cols ----
  for (int idx = tid; idx < 16 * 784; idx += NT) {
    int elem = idx / 784, r = idx - elem * 784;
    int t = r / 196, f = r - t * 196;
    float val = x[(size_t)(e0 + elem) * 784 + r];
    f16 hi = (f16)val;
    int vo = (elem * 4 + t) * 232 + f;
    vAhi[vo] = hi;
    vAlo[vo] = (f16)(val - (float)hi);
  }
  for (int p = tid; p < 64 * 36; p += NT) {
    int row = p / 36, c = 196 + (p - (p / 36) * 36);
    vAhi[row * 232 + c] = (f16)0;
    vAlo[row * 232 + c] = (f16)0;
  }
  __syncthreads();

  // ---- 8 capsule iterations ----
  #pragma unroll 1
  for (int it = 0; it < 8; ++it) {
    floatx4 acc[4][7];
    #pragma unroll
    for (int j = 0; j < 7; ++j) {
      float bb = bcap[(w + 4 * j) * 16 + l15];
      #pragma unroll
      for (int mt = 0; mt < 4; ++mt) acc[mt][j] = (floatx4){bb, bb, bb, bb};
    }
    #pragma unroll
    for (int ks = 0; ks < 7; ++ks) {
      half8 ah[4], al[4];
      #pragma unroll
      for (int mt = 0; mt < 4; ++mt) {
        int ao = (mt * 16 + l15) * 232 + ks * 32 + quad * 8;
        ah[mt] = *(const half8*)&vAhi[ao];
        al[mt] = *(const half8*)&vAlo[ao];
      }
      #pragma unroll
      for (int j = 0; j < 7; ++j) {
        int bo_ = ((w + 4 * j) * 16 + l15) * 224 + ks * 32 + quad * 8;
        half8 bh = *(const half8*)&Wch[bo_];
        half8 bl = *(const half8*)&Wcl[bo_];
        #pragma unroll
        for (int mt = 0; mt < 4; ++mt) {
          acc[mt][j] = __builtin_amdgcn_mfma_f32_16x16x32_f16(ah[mt], bh, acc[mt][j], 0, 0, 0);
          acc[mt][j] = __builtin_amdgcn_mfma_f32_16x16x32_f16(ah[mt], bl, acc[mt][j], 0, 0, 0);
          acc[mt][j] = __builtin_amdgcn_mfma_f32_16x16x32_f16(al[mt], bh, acc[mt][j], 0, 0, 0);
        }
      }
    }
    // ---- Z extraction: col 196 lives in ntile 12 = wave 0, j=3, l15==4 ----
    if (w == 0 && l15 == 4) {
      #pragma unroll
      for (int mt = 0; mt < 4; ++mt) {
        int elem = mt * 4 + quad;
        #pragma unroll
        for (int t = 0; t < 4; ++t) Zl[elem * 4 + t] = acc[mt][3][t];
      }
    }
    // ---- scores: S[t][s] = sum_j Y_t[j] * v_s[j], in-register + quad butterfly ----
    #pragma unroll
    for (int mt = 0; mt < 4; ++mt) {
      int elem = mt * 4 + quad;
      float part[16];
      #pragma unroll
      for (int i = 0; i < 16; ++i) part[i] = 0.f;
      #pragma unroll
      for (int j = 0; j < 7; ++j) {
        int nt = w + 4 * j;
        if (nt < 14) {
          int col = nt * 16 + l15;
          floatx4 c = acc[mt][j];
          #pragma unroll
          for (int s = 0; s < 4; ++s) {
            int vo = (elem * 4 + s) * 232 + col;
            float vv = (float)vAhi[vo] + (float)vAlo[vo];
            #pragma unroll
            for (int t = 0; t < 4; ++t) part[t * 4 + s] += c[t] * vv;
          }
        }
      }
      #pragma unroll
      for (int m = 1; m < 16; m <<= 1) {
        #pragma unroll
        for (int i = 0; i < 16; ++i) part[i] += __shfl_xor(part[i], m, 64);
      }
      if (l15 == 0) {
        #pragma unroll
        for (int i = 0; i < 16; ++i)
          Spart[(w * 64 + elem * 4 + (i >> 2)) * 4 + (i & 3)] = part[i];
      }
    }
    __syncthreads();
    // ---- combine partials + Z, softmax over s ----
    if (tid < 64) {
      int row = tid, elem = row >> 2;
      float sv[4];
      #pragma unroll
      for (int s = 0; s < 4; ++s)
        sv[s] = Spart[(0 * 64 + row) * 4 + s] + Spart[(1 * 64 + row) * 4 + s] +
                Spart[(2 * 64 + row) * 4 + s] + Spart[(3 * 64 + row) * 4 + s] +
                Zl[elem * 4 + s];
      float m = fmaxf(fmaxf(sv[0], sv[1]), fmaxf(sv[2], sv[3]));
      float ex0 = __expf(sv[0] - m), ex1 = __expf(sv[1] - m);
      float ex2 = __expf(sv[2] - m), ex3 = __expf(sv[3] - m);
      float inv = 1.f / (ex0 + ex1 + ex2 + ex3);
      Sful[row * 4 + 0] = ex0 * inv;
      Sful[row * 4 + 1] = ex1 * inv;
      Sful[row * 4 + 2] = ex2 * inv;
      Sful[row * 4 + 3] = ex3 * inv;
    }
    __syncthreads();
    // ---- PV: h[t][f] = sum_s p[t][s] * u[s][f] (u in C-regs), write hi/lo ----
    #pragma unroll
    for (int mt = 0; mt < 4; ++mt) {
      int elem = mt * 4 + quad;
      floatx4 p[4];
      #pragma unroll
      for (int t = 0; t < 4; ++t) p[t] = *(const floatx4*)&Sful[(elem * 4 + t) * 4];
      #pragma unroll
      for (int j = 0; j < 7; ++j) {
        int nt = w + 4 * j;
        if (nt >= 14) {
          int f = nt * 16 + l15 - 224;
          if (f < 196) {
            floatx4 u = acc[mt][j];
            #pragma unroll
            for (int t = 0; t < 4; ++t) {
              float h = p[t][0] * u[0] + p[t][1] * u[1] + p[t][2] * u[2] + p[t][3] * u[3];
              f16 hh = (f16)h;
              int vo = (elem * 4 + t) * 232 + f;
              vAhi[vo] = hh;
              vAlo[vo] = (f16)(h - (float)hh);
            }
          }
        }
      }
    }
    __syncthreads();
  }

  // ---------------- decoder (single fp16 MFMA) ----------------
  f16* d1s  = (f16*)smem;            // [16][808], aliases vAhi
  f16* hdec = (f16*)(smem + 29696);  // [16][808], aliases vAlo; later d2s
  float* lg = (float*)(smem + 59392);

  // h -> hdec (rows = elems, cols = t*196+f), single fp16 (hi part)
  for (int idx = tid; idx < 16 * 784; idx += NT) {
    int elem = idx / 784, r = idx - elem * 784;
    int t = r / 196, f = r - t * 196;
    hdec[elem * 808 + r] = vAhi[(elem * 4 + t) * 232 + f];
  }
  for (int p = tid; p < 16 * 16; p += NT) {
    int row = p >> 4, c = 784 + (p & 15);
    hdec[row * 808 + c] = (f16)0;
  }
  __syncthreads();

  floatx4 dacc[13];
  // ---- layer 1: relu(h Wd1^T + bd1) ----
  #pragma unroll
  for (int j = 0; j < 13; ++j) {
    int col = (w + 4 * j) * 16 + l15;
    float bb = (col < 784) ? bd1[col] : 0.f;
    dacc[j] = (floatx4){bb, bb, bb, bb};
  }
  #pragma unroll 5
  for (int ks = 0; ks < 25; ++ks) {
    half8 a = *(const half8*)&hdec[l15 * 808 + ks * 32 + quad * 8];
    #pragma unroll
    for (int j = 0; j < 13; ++j) {
      half8 b = *(const half8*)&Wd1[((w + 4 * j) * 16 + l15) * 800 + ks * 32 + quad * 8];
      dacc[j] = __builtin_amdgcn_mfma_f32_16x16x32_f16(a, b, dacc[j], 0, 0, 0);
    }
  }
  #pragma unroll
  for (int j = 0; j < 13; ++j) {
    int col = (w + 4 * j) * 16 + l15;
    if (col < 784) {
      #pragma unroll
      for (int t = 0; t < 4; ++t)
        d1s[(quad * 4 + t) * 808 + col] = (f16)fmaxf(dacc[j][t], 0.f);
    }
  }
  for (int p = tid; p < 16 * 16; p += NT) {
    int row = p >> 4, c = 784 + (p & 15);
    d1s[row * 808 + c] = (f16)0;
  }
  __syncthreads();
  // ---- layer 2: d1 Wd2^T + bd2 -> d2s (aliases hdec) ----
  f16* d2s = hdec;
  #pragma unroll
  for (int j = 0; j < 13; ++j) {
    int col = (w + 4 * j) * 16 + l15;
    float bb = (col < 784) ? bd2[col] : 0.f;
    dacc[j] = (floatx4){bb, bb, bb, bb};
  }
  #pragma unroll 5
  for (int ks = 0; ks < 25; ++ks) {
    half8 a = *(const half8*)&d1s[l15 * 808 + ks * 32 + quad * 8];
    #pragma unroll
    for (int j = 0; j < 13; ++j) {
      half8 b = *(const half8*)&Wd2[((w + 4 * j) * 16 + l15) * 800 + ks * 32 + quad * 8];
      dacc[j] = __builtin_amdgcn_mfma_f32_16x16x32_f16(a, b, dacc[j], 0, 0, 0);
    }
  }
  __syncthreads();
  #pragma unroll
  for (int j = 0; j < 13; ++j) {
    int col = (w + 4 * j) * 16 + l15;
    if (col < 784) {
      #pragma unroll
      for (int t = 0; t < 4; ++t)
        d2s[(quad * 4 + t) * 808 + col] = (f16)dacc[j][t];
    }
  }
  __syncthreads();
  // ---- logits + softmax ----
  if (tid < 160) {
    int elem = tid / 10, n = tid - (tid / 10) * 10;
    float s = bo[n];
    const f16* dp = &d2s[elem * 808];
    for (int f = 0; f < 784; ++f) s += (float)dp[f] * WoT[f * 16 + n];
    lg[elem * 10 + n] = s;
  }
  __syncthreads();
  if (tid < 16) {
    float l[10], m = -1e30f;
    #pragma unroll
    for (int n = 0; n < 10; ++n) { l[n] = lg[tid * 10 + n]; m = fmaxf(m, l[n]); }
    float sum = 0.f;
    #pragma unroll
    for (int n = 0; n < 10; ++n) { l[n] = __expf(l[n] - m); sum += l[n]; }
    float inv = 1.f / sum;
    #pragma unroll
    for (int n = 0; n < 10; ++n) out[(size_t)(e0 + tid) * 10 + n] = l[n] * inv;
  }
}

extern "C" void kernel_launch(void* const* d_in, const int* in_sizes, int n_in,
                              void* d_out, int out_size, void* d_ws, size_t ws_size,
                              hipStream_t stream) {
  const float* x   = (const float*)d_in[0];
  const float* W1  = (const float*)d_in[1];
  const float* b1  = (const float*)d_in[2];
  const float* W2  = (const float*)d_in[3];
  // b2 (d_in[4]) provably cancels in the softmax (row-constant) — unused.
  const float* W3  = (const float*)d_in[5];
  const float* b3  = (const float*)d_in[6];
  const float* Wd1 = (const float*)d_in[7];
  const float* bd1 = (const float*)d_in[8];
  const float* Wd2 = (const float*)d_in[9];
  const float* bd2 = (const float*)d_in[10];
  const float* Wo  = (const float*)d_in[11];
  const float* bo  = (const float*)d_in[12];
  float* out = (float*)d_out;

  char* ws = (char*)d_ws;
  f16*   Wch   = (f16*)ws;
  f16*   Wcl   = (f16*)(ws + WCAP_LO_OFF);
  float* bcap  = (float*)(ws + BCAP_OFF);
  f16*   Wd1h  = (f16*)(ws + WD1_OFF);
  f16*   Wd2h  = (f16*)(ws + WD2_OFF);
  float* WoTws = (float*)(ws + WOT_OFF);

  k_prep_wcap<<<(448 * 224 + NT - 1) / NT, NT, 0, stream>>>(W1, b1, W2, W3, b3, Wch, Wcl, bcap);
  k_prep_wd<<<(832 * 800 + NT - 1) / NT, NT, 0, stream>>>(Wd1, Wd1h);
  k_prep_wd<<<(832 * 800 + NT - 1) / NT, NT, 0, stream>>>(Wd2, Wd2h);
  k_prep_wo<<<(784 * 16 + NT - 1) / NT, NT, 0, stream>>>(Wo, WoTws);
  k_caps<<<32768 / 16, NT, 0, stream>>>(x, Wch, Wcl, bcap, Wd1h, bd1, Wd2h, bd2, WoTws, bo, out);
}

// Round 3
// 2993.641 us; speedup vs baseline: 1.7329x; 1.1120x over previous
//
#include <hip/hip_runtime.h>
#include <math.h>

#define NT 256
typedef _Float16 f16;
typedef _Float16 half8 __attribute__((ext_vector_type(8)));
typedef float floatx4 __attribute__((ext_vector_type(4)));

// ---------------- workspace layout (bytes) ----------------
#define WCAP_LO_OFF 200704            // Wcap_hi: 448*224*2 @ 0
#define BCAP_OFF    401408            // bcap: 448*4
#define WD1_OFF     403200            // Wd1p: 896*800*2 = 1433600
#define WD2_OFF     1836800           // Wd2p: 1433600
#define WOT_OFF     3270400           // WoT: 784*16*4 = 50176
#define HBUF_OFF    3321856           // h:  32768*800*2 = 52428800
#define D1_OFF      55750656          // d1: 32768*800*2 ; total ~108.2 MB

__device__ inline void glds16(const void* g, void* l) {
  __builtin_amdgcn_global_load_lds((const __attribute__((address_space(1))) void*)g,
                                   (__attribute__((address_space(3))) void*)l, 16, 0, 0);
}

// ---------------- prep kernels ----------------
// Wcap[n][k] (n<196: (W1^T W2)^T row; n==196: g[k]=sum_f b1[f]*W2[f][k]; 224<=n<420: W3), hi/lo fp16 split
__global__ void k_prep_wcap(const float* __restrict__ W1, const float* __restrict__ b1,
                            const float* __restrict__ W2,
                            const float* __restrict__ W3, const float* __restrict__ b3,
                            f16* __restrict__ Wch, f16* __restrict__ Wcl,
                            float* __restrict__ bcap) {
  int idx = blockIdx.x * NT + threadIdx.x;
  if (idx >= 448 * 224) return;
  int n = idx / 224, k = idx - n * 224;
  float v = 0.f;
  if (k < 196) {
    if (n < 196) {
      float s = 0.f;
      for (int f = 0; f < 196; ++f) s += W1[f * 196 + k] * W2[f * 196 + n];
      v = s;
    } else if (n == 196) {
      float s = 0.f;
      for (int f = 0; f < 196; ++f) s += b1[f] * W2[f * 196 + k];
      v = s;
    } else if (n >= 224 && n < 420) {
      v = W3[(n - 224) * 196 + k];
    }
  }
  f16 hi = (f16)v;
  Wch[idx] = hi;
  Wcl[idx] = (f16)(v - (float)hi);
  if (k == 0) bcap[n] = (n >= 224 && n < 420) ? b3[n - 224] : 0.f;
}

// Wdp[896][800] fp16, zero-padded beyond 784
__global__ void k_prep_wd(const float* __restrict__ Wd, f16* __restrict__ W16) {
  int idx = blockIdx.x * NT + threadIdx.x;
  if (idx >= 896 * 800) return;
  int n = idx / 800, k = idx - n * 800;
  W16[idx] = (f16)((n < 784 && k < 784) ? Wd[n * 784 + k] : 0.f);
}

// WoT[784][16] fp32 (n<10 valid)
__global__ void k_prep_wo(const float* __restrict__ Wo, float* __restrict__ WoT) {
  int idx = blockIdx.x * NT + threadIdx.x;
  if (idx >= 784 * 16) return;
  int f = idx >> 4, n = idx & 15;
  WoT[idx] = (n < 10) ? Wo[n * 784 + f] : 0.f;
}

// ---------------- capsule recurrence (split-fp16 MFMA), writes h fp16 ----------------
__global__ __launch_bounds__(NT, 2)
void k_caps(const float* __restrict__ x,
            const f16* __restrict__ Wch, const f16* __restrict__ Wcl,
            const float* __restrict__ bcap,
            f16* __restrict__ hbuf) {
  __shared__ __align__(16) char smem[64768];
  f16*   vAhi  = (f16*)smem;                 // [64][232]
  f16*   vAlo  = (f16*)(smem + 29696);       // [64][232]
  float* Spart = (float*)(smem + 59392);     // [4][64][4]
  float* Sful  = (float*)(smem + 63488);     // [64][4]
  float* Zl    = (float*)(smem + 64512);     // [64]

  const int tid  = threadIdx.x;
  const int w    = tid >> 6;
  const int lane = tid & 63;
  const int l15  = lane & 15;
  const int quad = lane >> 4;
  const int e0   = blockIdx.x * 16;

  for (int idx = tid; idx < 16 * 784; idx += NT) {
    int elem = idx / 784, r = idx - elem * 784;
    int t = r / 196, f = r - t * 196;
    float val = x[(size_t)(e0 + elem) * 784 + r];
    f16 hi = (f16)val;
    int vo = (elem * 4 + t) * 232 + f;
    vAhi[vo] = hi;
    vAlo[vo] = (f16)(val - (float)hi);
  }
  for (int p = tid; p < 64 * 36; p += NT) {
    int row = p / 36, c = 196 + (p - (p / 36) * 36);
    vAhi[row * 232 + c] = (f16)0;
    vAlo[row * 232 + c] = (f16)0;
  }
  __syncthreads();

  #pragma unroll 1
  for (int it = 0; it < 8; ++it) {
    floatx4 acc[4][7];
    #pragma unroll
    for (int j = 0; j < 7; ++j) {
      float bb = bcap[(w + 4 * j) * 16 + l15];
      #pragma unroll
      for (int mt = 0; mt < 4; ++mt) acc[mt][j] = (floatx4){bb, bb, bb, bb};
    }
    #pragma unroll
    for (int ks = 0; ks < 7; ++ks) {
      half8 ah[4], al[4];
      #pragma unroll
      for (int mt = 0; mt < 4; ++mt) {
        int ao = (mt * 16 + l15) * 232 + ks * 32 + quad * 8;
        ah[mt] = *(const half8*)&vAhi[ao];
        al[mt] = *(const half8*)&vAlo[ao];
      }
      #pragma unroll
      for (int j = 0; j < 7; ++j) {
        int bo_ = ((w + 4 * j) * 16 + l15) * 224 + ks * 32 + quad * 8;
        half8 bh = *(const half8*)&Wch[bo_];
        half8 bl = *(const half8*)&Wcl[bo_];
        #pragma unroll
        for (int mt = 0; mt < 4; ++mt) {
          acc[mt][j] = __builtin_amdgcn_mfma_f32_16x16x32_f16(ah[mt], bh, acc[mt][j], 0, 0, 0);
          acc[mt][j] = __builtin_amdgcn_mfma_f32_16x16x32_f16(ah[mt], bl, acc[mt][j], 0, 0, 0);
          acc[mt][j] = __builtin_amdgcn_mfma_f32_16x16x32_f16(al[mt], bh, acc[mt][j], 0, 0, 0);
        }
      }
    }
    if (w == 0 && l15 == 4) {
      #pragma unroll
      for (int mt = 0; mt < 4; ++mt) {
        int elem = mt * 4 + quad;
        #pragma unroll
        for (int t = 0; t < 4; ++t) Zl[elem * 4 + t] = acc[mt][3][t];
      }
    }
    #pragma unroll
    for (int mt = 0; mt < 4; ++mt) {
      int elem = mt * 4 + quad;
      float part[16];
      #pragma unroll
      for (int i = 0; i < 16; ++i) part[i] = 0.f;
      #pragma unroll
      for (int j = 0; j < 7; ++j) {
        int nt = w + 4 * j;
        if (nt < 14) {
          int col = nt * 16 + l15;
          floatx4 c = acc[mt][j];
          #pragma unroll
          for (int s = 0; s < 4; ++s) {
            int vo = (elem * 4 + s) * 232 + col;
            float vv = (float)vAhi[vo] + (float)vAlo[vo];
            #pragma unroll
            for (int t = 0; t < 4; ++t) part[t * 4 + s] += c[t] * vv;
          }
        }
      }
      #pragma unroll
      for (int m = 1; m < 16; m <<= 1) {
        #pragma unroll
        for (int i = 0; i < 16; ++i) part[i] += __shfl_xor(part[i], m, 64);
      }
      if (l15 == 0) {
        #pragma unroll
        for (int i = 0; i < 16; ++i)
          Spart[(w * 64 + elem * 4 + (i >> 2)) * 4 + (i & 3)] = part[i];
      }
    }
    __syncthreads();
    if (tid < 64) {
      int row = tid, elem = row >> 2;
      float sv[4];
      #pragma unroll
      for (int s = 0; s < 4; ++s)
        sv[s] = Spart[(0 * 64 + row) * 4 + s] + Spart[(1 * 64 + row) * 4 + s] +
                Spart[(2 * 64 + row) * 4 + s] + Spart[(3 * 64 + row) * 4 + s] +
                Zl[elem * 4 + s];
      float m = fmaxf(fmaxf(sv[0], sv[1]), fmaxf(sv[2], sv[3]));
      float ex0 = __expf(sv[0] - m), ex1 = __expf(sv[1] - m);
      float ex2 = __expf(sv[2] - m), ex3 = __expf(sv[3] - m);
      float inv = 1.f / (ex0 + ex1 + ex2 + ex3);
      Sful[row * 4 + 0] = ex0 * inv;
      Sful[row * 4 + 1] = ex1 * inv;
      Sful[row * 4 + 2] = ex2 * inv;
      Sful[row * 4 + 3] = ex3 * inv;
    }
    __syncthreads();
    #pragma unroll
    for (int mt = 0; mt < 4; ++mt) {
      int elem = mt * 4 + quad;
      floatx4 p[4];
      #pragma unroll
      for (int t = 0; t < 4; ++t) p[t] = *(const floatx4*)&Sful[(elem * 4 + t) * 4];
      #pragma unroll
      for (int j = 0; j < 7; ++j) {
        int nt = w + 4 * j;
        if (nt >= 14) {
          int f = nt * 16 + l15 - 224;
          if (f < 196) {
            floatx4 u = acc[mt][j];
            #pragma unroll
            for (int t = 0; t < 4; ++t) {
              float h = p[t][0] * u[0] + p[t][1] * u[1] + p[t][2] * u[2] + p[t][3] * u[3];
              f16 hh = (f16)h;
              int vo = (elem * 4 + t) * 232 + f;
              vAhi[vo] = hh;
              vAlo[vo] = (f16)(h - (float)hh);
            }
          }
        }
      }
    }
    __syncthreads();
  }

  // ---- write h (hi part) to global [32768][800], pad cols zeroed ----
  for (int idx = tid; idx < 16 * 800; idx += NT) {
    int elem = idx / 800, r = idx - elem * 800;
    f16 v = (f16)0;
    if (r < 784) { int t = r / 196, f = r - t * 196; v = vAhi[(elem * 4 + t) * 232 + f]; }
    hbuf[(size_t)(e0 + elem) * 800 + r] = v;
  }
}

// ---------------- decoder layer GEMM: C[32768 x <800] = A[32768x800] * Bw[896x800]^T ----------------
// 128x128 tile, BK=32, global_load_lds staging, bias+optional relu epilogue.
__global__ __launch_bounds__(NT, 2)
void k_dec(const f16* __restrict__ A, const f16* __restrict__ Bw,
           const float* __restrict__ bias, f16* __restrict__ C, int do_relu) {
  __shared__ __align__(16) f16 As[128 * 32];
  __shared__ __align__(16) f16 Bs[128 * 32];
  const int tid = threadIdx.x, w = tid >> 6, lane = tid & 63;
  const int l15 = lane & 15, quad = lane >> 4;
  const int m0 = blockIdx.x * 128, n0 = blockIdx.y * 128;
  const int wm = w & 1, wn = w >> 1;
  const int srow = lane >> 2, soff = (lane & 3) * 8;  // staging: 16 rows x 4 lanes x 16B

  floatx4 acc[4][4];
  #pragma unroll
  for (int nt = 0; nt < 4; ++nt) {
    int col = n0 + wn * 64 + nt * 16 + l15;
    float bb = (col < 784) ? bias[col] : 0.f;
    #pragma unroll
    for (int mt = 0; mt < 4; ++mt) acc[mt][nt] = (floatx4){bb, bb, bb, bb};
  }

  for (int kk = 0; kk < 25; ++kk) {
    __syncthreads();
    #pragma unroll
    for (int i = 0; i < 2; ++i) {
      int r = w * 32 + i * 16;
      glds16(&A[(size_t)(m0 + r + srow) * 800 + kk * 32 + soff], &As[r * 32]);
      glds16(&Bw[(size_t)(n0 + r + srow) * 800 + kk * 32 + soff], &Bs[r * 32]);
    }
    __syncthreads();
    half8 af[4], bf[4];
    #pragma unroll
    for (int mt = 0; mt < 4; ++mt)
      af[mt] = *(const half8*)&As[(wm * 64 + mt * 16 + l15) * 32 + quad * 8];
    #pragma unroll
    for (int nt = 0; nt < 4; ++nt)
      bf[nt] = *(const half8*)&Bs[(wn * 64 + nt * 16 + l15) * 32 + quad * 8];
    #pragma unroll
    for (int mt = 0; mt < 4; ++mt)
      #pragma unroll
      for (int nt = 0; nt < 4; ++nt)
        acc[mt][nt] = __builtin_amdgcn_mfma_f32_16x16x32_f16(af[mt], bf[nt], acc[mt][nt], 0, 0, 0);
  }

  #pragma unroll
  for (int nt = 0; nt < 4; ++nt) {
    int gcol = n0 + wn * 64 + nt * 16 + l15;
    if (gcol < 800) {
      #pragma unroll
      for (int mt = 0; mt < 4; ++mt) {
        #pragma unroll
        for (int r = 0; r < 4; ++r) {
          int grow = m0 + wm * 64 + mt * 16 + quad * 4 + r;
          float v = acc[mt][nt][r];
          if (do_relu) v = fmaxf(v, 0.f);
          C[(size_t)grow * 800 + gcol] = (f16)v;
        }
      }
    }
  }
}

// ---------------- logits + softmax ----------------
__global__ __launch_bounds__(NT, 4)
void k_logits(const f16* __restrict__ d2, const float* __restrict__ WoT,
              const float* __restrict__ bo, float* __restrict__ out) {
  __shared__ __align__(16) f16 ds[16 * 800];
  __shared__ float lg[160];
  const int tid = threadIdx.x;
  const size_t e0 = (size_t)blockIdx.x * 16;
  for (int i = tid; i < 16 * 98; i += NT) {
    int e = i / 98, c = (i - e * 98) * 8;
    *(half8*)&ds[e * 800 + c] = *(const half8*)&d2[(e0 + e) * 800 + c];
  }
  __syncthreads();
  {
    int e = tid >> 4, n = tid & 15;
    const f16* dp = &ds[e * 800];
    float s = 0.f;
    #pragma unroll 4
    for (int f = 0; f < 784; ++f) s += (float)dp[f] * WoT[f * 16 + n];
    if (n < 10) lg[e * 10 + n] = s + bo[n];
  }
  __syncthreads();
  if (tid < 16) {
    float l[10], m = -1e30f;
    #pragma unroll
    for (int n = 0; n < 10; ++n) { l[n] = lg[tid * 10 + n]; m = fmaxf(m, l[n]); }
    float sum = 0.f;
    #pragma unroll
    for (int n = 0; n < 10; ++n) { l[n] = __expf(l[n] - m); sum += l[n]; }
    float inv = 1.f / sum;
    #pragma unroll
    for (int n = 0; n < 10; ++n) out[(e0 + tid) * 10 + n] = l[n] * inv;
  }
}

extern "C" void kernel_launch(void* const* d_in, const int* in_sizes, int n_in,
                              void* d_out, int out_size, void* d_ws, size_t ws_size,
                              hipStream_t stream) {
  const float* x   = (const float*)d_in[0];
  const float* W1  = (const float*)d_in[1];
  const float* b1  = (const float*)d_in[2];
  const float* W2  = (const float*)d_in[3];
  // b2 (d_in[4]) cancels in the softmax (row-constant) — unused.
  const float* W3  = (const float*)d_in[5];
  const float* b3  = (const float*)d_in[6];
  const float* Wd1 = (const float*)d_in[7];
  const float* bd1 = (const float*)d_in[8];
  const float* Wd2 = (const float*)d_in[9];
  const float* bd2 = (const float*)d_in[10];
  const float* Wo  = (const float*)d_in[11];
  const float* bo  = (const float*)d_in[12];
  float* out = (float*)d_out;

  char* ws = (char*)d_ws;
  f16*   Wch   = (f16*)ws;
  f16*   Wcl   = (f16*)(ws + WCAP_LO_OFF);
  float* bcap  = (float*)(ws + BCAP_OFF);
  f16*   Wd1p  = (f16*)(ws + WD1_OFF);
  f16*   Wd2p  = (f16*)(ws + WD2_OFF);
  float* WoTws = (float*)(ws + WOT_OFF);
  f16*   hbuf  = (f16*)(ws + HBUF_OFF);
  f16*   d1buf = (f16*)(ws + D1_OFF);

  k_prep_wcap<<<(448 * 224 + NT - 1) / NT, NT, 0, stream>>>(W1, b1, W2, W3, b3, Wch, Wcl, bcap);
  k_prep_wd<<<(896 * 800 + NT - 1) / NT, NT, 0, stream>>>(Wd1, Wd1p);
  k_prep_wd<<<(896 * 800 + NT - 1) / NT, NT, 0, stream>>>(Wd2, Wd2p);
  k_prep_wo<<<(784 * 16 + NT - 1) / NT, NT, 0, stream>>>(Wo, WoTws);

  k_caps<<<32768 / 16, NT, 0, stream>>>(x, Wch, Wcl, bcap, hbuf);
  k_dec<<<dim3(32768 / 128, 7), NT, 0, stream>>>(hbuf, Wd1p, bd1, d1buf, 1);
  k_dec<<<dim3(32768 / 128, 7), NT, 0, stream>>>(d1buf, Wd2p, bd2, hbuf, 0);  // d2 -> hbuf
  k_logits<<<32768 / 16, NT, 0, stream>>>(hbuf, WoTws, bo, out);
}

// Round 4
// 1189.600 us; speedup vs baseline: 4.3608x; 2.5165x over previous
//
#include <hip/hip_runtime.h>
#include <math.h>

#define NT 256
typedef _Float16 f16;
typedef _Float16 half8 __attribute__((ext_vector_type(8)));
typedef float floatx4 __attribute__((ext_vector_type(4)));

// ---------------- workspace layout (bytes) ----------------
#define WCAP_LO_OFF 200704            // Wcap_hi: 448*224*2 @ 0
#define BCAP_OFF    401408            // bcap: 448*4
#define WD1_OFF     403200            // Wd1p: 896*800*2 = 1433600
#define WD2_OFF     1836800           // Wd2p: 1433600
#define WOT_OFF     3270400           // WoT: 784*16*4 = 50176
#define HBUF_OFF    3321856           // h:  32768*800*2 = 52428800
#define D1_OFF      55750656          // d1: 32768*800*2 ; total ~108.2 MB

__device__ inline void glds16(const void* g, void* l) {
  __builtin_amdgcn_global_load_lds((const __attribute__((address_space(1))) void*)g,
                                   (__attribute__((address_space(3))) void*)l, 16, 0, 0);
}

// ---------------- prep kernels ----------------
__global__ void k_prep_wcap(const float* __restrict__ W1, const float* __restrict__ b1,
                            const float* __restrict__ W2,
                            const float* __restrict__ W3, const float* __restrict__ b3,
                            f16* __restrict__ Wch, f16* __restrict__ Wcl,
                            float* __restrict__ bcap) {
  int idx = blockIdx.x * NT + threadIdx.x;
  if (idx >= 448 * 224) return;
  int n = idx / 224, k = idx - n * 224;
  float v = 0.f;
  if (k < 196) {
    if (n < 196) {
      float s = 0.f;
      for (int f = 0; f < 196; ++f) s += W1[f * 196 + k] * W2[f * 196 + n];
      v = s;
    } else if (n == 196) {
      float s = 0.f;
      for (int f = 0; f < 196; ++f) s += b1[f] * W2[f * 196 + k];
      v = s;
    } else if (n >= 224 && n < 420) {
      v = W3[(n - 224) * 196 + k];
    }
  }
  f16 hi = (f16)v;
  Wch[idx] = hi;
  Wcl[idx] = (f16)(v - (float)hi);
  if (k == 0) bcap[n] = (n >= 224 && n < 420) ? b3[n - 224] : 0.f;
}

__global__ void k_prep_wd(const float* __restrict__ Wd, f16* __restrict__ W16) {
  int idx = blockIdx.x * NT + threadIdx.x;
  if (idx >= 896 * 800) return;
  int n = idx / 800, k = idx - n * 800;
  W16[idx] = (f16)((n < 784 && k < 784) ? Wd[n * 784 + k] : 0.f);
}

__global__ void k_prep_wo(const float* __restrict__ Wo, float* __restrict__ WoT) {
  int idx = blockIdx.x * NT + threadIdx.x;
  if (idx >= 784 * 16) return;
  int f = idx >> 4, n = idx & 15;
  WoT[idx] = (n < 10) ? Wo[n * 784 + f] : 0.f;
}

// ---------------- capsule recurrence (phase-split, spill-free) ----------------
// Phase A: Y = v*G (+Z col), acc[4][4]; score reduce; softmax; Phase D: u = v*W3^T, acu[4][4]; PV.
__global__ __launch_bounds__(NT, 2)
void k_caps(const float* __restrict__ x,
            const f16* __restrict__ Wch, const f16* __restrict__ Wcl,
            const float* __restrict__ bcap,
            f16* __restrict__ hbuf) {
  __shared__ __align__(16) char smem[64768];
  f16*   vAhi  = (f16*)smem;                 // [64][232]
  f16*   vAlo  = (f16*)(smem + 29696);       // [64][232]
  float* Spart = (float*)(smem + 59392);     // [4][64][4]
  float* Sful  = (float*)(smem + 63488);     // [64][4]
  float* Zl    = (float*)(smem + 64512);     // [64]

  const int tid  = threadIdx.x;
  const int w    = tid >> 6;
  const int lane = tid & 63;
  const int l15  = lane & 15;
  const int quad = lane >> 4;
  const int e0   = blockIdx.x * 16;

  for (int idx = tid; idx < 16 * 784; idx += NT) {
    int elem = idx / 784, r = idx - elem * 784;
    int t = r / 196, f = r - t * 196;
    float val = x[(size_t)(e0 + elem) * 784 + r];
    f16 hi = (f16)val;
    int vo = (elem * 4 + t) * 232 + f;
    vAhi[vo] = hi;
    vAlo[vo] = (f16)(val - (float)hi);
  }
  for (int p = tid; p < 64 * 36; p += NT) {
    int row = p / 36, c = 196 + (p - (p / 36) * 36);
    vAhi[row * 232 + c] = (f16)0;
    vAlo[row * 232 + c] = (f16)0;
  }
  __syncthreads();

  // u bias (constant across iterations): ntile 14+w+4j, rows 224..447
  float ubias[4];
  #pragma unroll
  for (int j = 0; j < 4; ++j) {
    int nt = 14 + w + 4 * j;
    ubias[j] = (nt < 27) ? bcap[nt * 16 + l15] : 0.f;
  }

  #pragma unroll 1
  for (int it = 0; it < 8; ++it) {
    // ---------- Phase A: Y GEMM [64 x 208] (ntiles 0..12; Y bias == 0) ----------
    {
      floatx4 acc[4][4];
      #pragma unroll
      for (int mt = 0; mt < 4; ++mt)
        #pragma unroll
        for (int j = 0; j < 4; ++j) acc[mt][j] = (floatx4){0.f, 0.f, 0.f, 0.f};
      #pragma unroll
      for (int ks = 0; ks < 7; ++ks) {
        half8 ah[4], al[4];
        #pragma unroll
        for (int mt = 0; mt < 4; ++mt) {
          int ao = (mt * 16 + l15) * 232 + ks * 32 + quad * 8;
          ah[mt] = *(const half8*)&vAhi[ao];
          al[mt] = *(const half8*)&vAlo[ao];
        }
        #pragma unroll
        for (int j = 0; j < 4; ++j) {
          int nt = w + 4 * j;
          if (nt < 13) {                       // wave-uniform branch
            int bo_ = (nt * 16 + l15) * 224 + ks * 32 + quad * 8;
            half8 bh = *(const half8*)&Wch[bo_];
            half8 bl = *(const half8*)&Wcl[bo_];
            #pragma unroll
            for (int mt = 0; mt < 4; ++mt) {
              acc[mt][j] = __builtin_amdgcn_mfma_f32_16x16x32_f16(ah[mt], bh, acc[mt][j], 0, 0, 0);
              acc[mt][j] = __builtin_amdgcn_mfma_f32_16x16x32_f16(ah[mt], bl, acc[mt][j], 0, 0, 0);
              acc[mt][j] = __builtin_amdgcn_mfma_f32_16x16x32_f16(al[mt], bh, acc[mt][j], 0, 0, 0);
            }
          }
        }
      }
      // Z col 196 = ntile 12 (w==0, j==3), l15==4
      if (w == 0 && l15 == 4) {
        #pragma unroll
        for (int mt = 0; mt < 4; ++mt) {
          int elem = mt * 4 + quad;
          #pragma unroll
          for (int t = 0; t < 4; ++t) Zl[elem * 4 + t] = acc[mt][3][t];
        }
      }
      // score partials: S[t][s] += Y_t[col] * v_s[col]
      #pragma unroll
      for (int mt = 0; mt < 4; ++mt) {
        int elem = mt * 4 + quad;
        float part[16];
        #pragma unroll
        for (int i = 0; i < 16; ++i) part[i] = 0.f;
        #pragma unroll
        for (int j = 0; j < 4; ++j) {
          int nt = w + 4 * j;
          if (nt < 13) {
            int col = nt * 16 + l15;
            floatx4 c = acc[mt][j];
            #pragma unroll
            for (int s = 0; s < 4; ++s) {
              int vo = (elem * 4 + s) * 232 + col;
              float vv = (float)vAhi[vo] + (float)vAlo[vo];
              #pragma unroll
              for (int t = 0; t < 4; ++t) part[t * 4 + s] += c[t] * vv;
            }
          }
        }
        #pragma unroll
        for (int m = 1; m < 16; m <<= 1) {
          #pragma unroll
          for (int i = 0; i < 16; ++i) part[i] += __shfl_xor(part[i], m, 64);
        }
        if (l15 == 0) {
          #pragma unroll
          for (int i = 0; i < 16; ++i)
            Spart[(w * 64 + elem * 4 + (i >> 2)) * 4 + (i & 3)] = part[i];
        }
      }
    }
    __syncthreads();
    // ---------- softmax ----------
    if (tid < 64) {
      int row = tid, elem = row >> 2;
      float sv[4];
      #pragma unroll
      for (int s = 0; s < 4; ++s)
        sv[s] = Spart[(0 * 64 + row) * 4 + s] + Spart[(1 * 64 + row) * 4 + s] +
                Spart[(2 * 64 + row) * 4 + s] + Spart[(3 * 64 + row) * 4 + s] +
                Zl[elem * 4 + s];
      float m = fmaxf(fmaxf(sv[0], sv[1]), fmaxf(sv[2], sv[3]));
      float ex0 = __expf(sv[0] - m), ex1 = __expf(sv[1] - m);
      float ex2 = __expf(sv[2] - m), ex3 = __expf(sv[3] - m);
      float inv = 1.f / (ex0 + ex1 + ex2 + ex3);
      Sful[row * 4 + 0] = ex0 * inv;
      Sful[row * 4 + 1] = ex1 * inv;
      Sful[row * 4 + 2] = ex2 * inv;
      Sful[row * 4 + 3] = ex3 * inv;
    }
    __syncthreads();
    // ---------- Phase D: u GEMM [64 x 208] (ntiles 14..26) ----------
    floatx4 acu[4][4];
    #pragma unroll
    for (int mt = 0; mt < 4; ++mt)
      #pragma unroll
      for (int j = 0; j < 4; ++j)
        acu[mt][j] = (floatx4){ubias[j], ubias[j], ubias[j], ubias[j]};
    #pragma unroll
    for (int ks = 0; ks < 7; ++ks) {
      half8 ah[4], al[4];
      #pragma unroll
      for (int mt = 0; mt < 4; ++mt) {
        int ao = (mt * 16 + l15) * 232 + ks * 32 + quad * 8;
        ah[mt] = *(const half8*)&vAhi[ao];
        al[mt] = *(const half8*)&vAlo[ao];
      }
      #pragma unroll
      for (int j = 0; j < 4; ++j) {
        int nt = 14 + w + 4 * j;
        if (nt < 27) {
          int bo_ = (nt * 16 + l15) * 224 + ks * 32 + quad * 8;
          half8 bh = *(const half8*)&Wch[bo_];
          half8 bl = *(const half8*)&Wcl[bo_];
          #pragma unroll
          for (int mt = 0; mt < 4; ++mt) {
            acu[mt][j] = __builtin_amdgcn_mfma_f32_16x16x32_f16(ah[mt], bh, acu[mt][j], 0, 0, 0);
            acu[mt][j] = __builtin_amdgcn_mfma_f32_16x16x32_f16(ah[mt], bl, acu[mt][j], 0, 0, 0);
            acu[mt][j] = __builtin_amdgcn_mfma_f32_16x16x32_f16(al[mt], bh, acu[mt][j], 0, 0, 0);
          }
        }
      }
    }
    __syncthreads();   // all vA reads (GEMM) done before PV overwrites
    // ---------- PV: h[t][f] = sum_s p[t][s]*u[s][f] ----------
    #pragma unroll
    for (int mt = 0; mt < 4; ++mt) {
      int elem = mt * 4 + quad;
      floatx4 p[4];
      #pragma unroll
      for (int t = 0; t < 4; ++t) p[t] = *(const floatx4*)&Sful[(elem * 4 + t) * 4];
      #pragma unroll
      for (int j = 0; j < 4; ++j) {
        int nt = 14 + w + 4 * j;
        if (nt < 27) {
          int f = (w + 4 * j) * 16 + l15;
          if (f < 196) {
            floatx4 u = acu[mt][j];
            #pragma unroll
            for (int t = 0; t < 4; ++t) {
              float h = p[t][0] * u[0] + p[t][1] * u[1] + p[t][2] * u[2] + p[t][3] * u[3];
              f16 hh = (f16)h;
              int vo = (elem * 4 + t) * 232 + f;
              vAhi[vo] = hh;
              vAlo[vo] = (f16)(h - (float)hh);
            }
          }
        }
      }
    }
    __syncthreads();
  }

  // ---- write h (hi part) to global [32768][800] ----
  for (int idx = tid; idx < 16 * 800; idx += NT) {
    int elem = idx / 800, r = idx - elem * 800;
    f16 v = (f16)0;
    if (r < 784) { int t = r / 196, f = r - t * 196; v = vAhi[(elem * 4 + t) * 232 + f]; }
    hbuf[(size_t)(e0 + elem) * 800 + r] = v;
  }
}

// ---------------- decoder layer GEMM (unchanged) ----------------
__global__ __launch_bounds__(NT, 2)
void k_dec(const f16* __restrict__ A, const f16* __restrict__ Bw,
           const float* __restrict__ bias, f16* __restrict__ C, int do_relu) {
  __shared__ __align__(16) f16 As[128 * 32];
  __shared__ __align__(16) f16 Bs[128 * 32];
  const int tid = threadIdx.x, w = tid >> 6, lane = tid & 63;
  const int l15 = lane & 15, quad = lane >> 4;
  const int m0 = blockIdx.x * 128, n0 = blockIdx.y * 128;
  const int wm = w & 1, wn = w >> 1;
  const int srow = lane >> 2, soff = (lane & 3) * 8;

  floatx4 acc[4][4];
  #pragma unroll
  for (int nt = 0; nt < 4; ++nt) {
    int col = n0 + wn * 64 + nt * 16 + l15;
    float bb = (col < 784) ? bias[col] : 0.f;
    #pragma unroll
    for (int mt = 0; mt < 4; ++mt) acc[mt][nt] = (floatx4){bb, bb, bb, bb};
  }

  for (int kk = 0; kk < 25; ++kk) {
    __syncthreads();
    #pragma unroll
    for (int i = 0; i < 2; ++i) {
      int r = w * 32 + i * 16;
      glds16(&A[(size_t)(m0 + r + srow) * 800 + kk * 32 + soff], &As[r * 32]);
      glds16(&Bw[(size_t)(n0 + r + srow) * 800 + kk * 32 + soff], &Bs[r * 32]);
    }
    __syncthreads();
    half8 af[4], bf[4];
    #pragma unroll
    for (int mt = 0; mt < 4; ++mt)
      af[mt] = *(const half8*)&As[(wm * 64 + mt * 16 + l15) * 32 + quad * 8];
    #pragma unroll
    for (int nt = 0; nt < 4; ++nt)
      bf[nt] = *(const half8*)&Bs[(wn * 64 + nt * 16 + l15) * 32 + quad * 8];
    #pragma unroll
    for (int mt = 0; mt < 4; ++mt)
      #pragma unroll
      for (int nt = 0; nt < 4; ++nt)
        acc[mt][nt] = __builtin_amdgcn_mfma_f32_16x16x32_f16(af[mt], bf[nt], acc[mt][nt], 0, 0, 0);
  }

  #pragma unroll
  for (int nt = 0; nt < 4; ++nt) {
    int gcol = n0 + wn * 64 + nt * 16 + l15;
    if (gcol < 800) {
      #pragma unroll
      for (int mt = 0; mt < 4; ++mt) {
        #pragma unroll
        for (int r = 0; r < 4; ++r) {
          int grow = m0 + wm * 64 + mt * 16 + quad * 4 + r;
          float v = acc[mt][nt][r];
          if (do_relu) v = fmaxf(v, 0.f);
          C[(size_t)grow * 800 + gcol] = (f16)v;
        }
      }
    }
  }
}

// ---------------- logits + softmax (unchanged) ----------------
__global__ __launch_bounds__(NT, 4)
void k_logits(const f16* __restrict__ d2, const float* __restrict__ WoT,
              const float* __restrict__ bo, float* __restrict__ out) {
  __shared__ __align__(16) f16 ds[16 * 800];
  __shared__ float lg[160];
  const int tid = threadIdx.x;
  const size_t e0 = (size_t)blockIdx.x * 16;
  for (int i = tid; i < 16 * 98; i += NT) {
    int e = i / 98, c = (i - e * 98) * 8;
    *(half8*)&ds[e * 800 + c] = *(const half8*)&d2[(e0 + e) * 800 + c];
  }
  __syncthreads();
  {
    int e = tid >> 4, n = tid & 15;
    const f16* dp = &ds[e * 800];
    float s = 0.f;
    #pragma unroll 4
    for (int f = 0; f < 784; ++f) s += (float)dp[f] * WoT[f * 16 + n];
    if (n < 10) lg[e * 10 + n] = s + bo[n];
  }
  __syncthreads();
  if (tid < 16) {
    float l[10], m = -1e30f;
    #pragma unroll
    for (int n = 0; n < 10; ++n) { l[n] = lg[tid * 10 + n]; m = fmaxf(m, l[n]); }
    float sum = 0.f;
    #pragma unroll
    for (int n = 0; n < 10; ++n) { l[n] = __expf(l[n] - m); sum += l[n]; }
    float inv = 1.f / sum;
    #pragma unroll
    for (int n = 0; n < 10; ++n) out[(e0 + tid) * 10 + n] = l[n] * inv;
  }
}

extern "C" void kernel_launch(void* const* d_in, const int* in_sizes, int n_in,
                              void* d_out, int out_size, void* d_ws, size_t ws_size,
                              hipStream_t stream) {
  const float* x   = (const float*)d_in[0];
  const float* W1  = (const float*)d_in[1];
  const float* b1  = (const float*)d_in[2];
  const float* W2  = (const float*)d_in[3];
  // b2 (d_in[4]) cancels in the softmax (row-constant) — unused.
  const float* W3  = (const float*)d_in[5];
  const float* b3  = (const float*)d_in[6];
  const float* Wd1 = (const float*)d_in[7];
  const float* bd1 = (const float*)d_in[8];
  const float* Wd2 = (const float*)d_in[9];
  const float* bd2 = (const float*)d_in[10];
  const float* Wo  = (const float*)d_in[11];
  const float* bo  = (const float*)d_in[12];
  float* out = (float*)d_out;

  char* ws = (char*)d_ws;
  f16*   Wch   = (f16*)ws;
  f16*   Wcl   = (f16*)(ws + WCAP_LO_OFF);
  float* bcap  = (float*)(ws + BCAP_OFF);
  f16*   Wd1p  = (f16*)(ws + WD1_OFF);
  f16*   Wd2p  = (f16*)(ws + WD2_OFF);
  float* WoTws = (float*)(ws + WOT_OFF);
  f16*   hbuf  = (f16*)(ws + HBUF_OFF);
  f16*   d1buf = (f16*)(ws + D1_OFF);

  k_prep_wcap<<<(448 * 224 + NT - 1) / NT, NT, 0, stream>>>(W1, b1, W2, W3, b3, Wch, Wcl, bcap);
  k_prep_wd<<<(896 * 800 + NT - 1) / NT, NT, 0, stream>>>(Wd1, Wd1p);
  k_prep_wd<<<(896 * 800 + NT - 1) / NT, NT, 0, stream>>>(Wd2, Wd2p);
  k_prep_wo<<<(784 * 16 + NT - 1) / NT, NT, 0, stream>>>(Wo, WoTws);

  k_caps<<<32768 / 16, NT, 0, stream>>>(x, Wch, Wcl, bcap, hbuf);
  k_dec<<<dim3(32768 / 128, 7), NT, 0, stream>>>(hbuf, Wd1p, bd1, d1buf, 1);
  k_dec<<<dim3(32768 / 128, 7), NT, 0, stream>>>(d1buf, Wd2p, bd2, hbuf, 0);
  k_logits<<<32768 / 16, NT, 0, stream>>>(hbuf, WoTws, bo, out);
}